// Round 2
// baseline (474.796 us; speedup 1.0000x reference)
//
#include <hip/hip_runtime.h>
#include <cstdint>
#include <cstddef>

#define T_TOKENS 8192
#define K_DIM 4096
#define N_DIM 4096

using i32x4 = __attribute__((ext_vector_type(4))) int;

// ---------------------------------------------------------------------------
// Kernel 0: pack harness-delivered int32 weight (one int8 value per int32
// element — "integer -> const int*") into a dense int8 [N][K] matrix.
// ---------------------------------------------------------------------------
__global__ __launch_bounds__(256) void pack_weight(const int* __restrict__ win,
                                                   int8_t* __restrict__ wout) {
    const int idx = blockIdx.x * 256 + threadIdx.x;  // one dword (4 int8) out
    const i32x4 v = reinterpret_cast<const i32x4*>(win)[idx];
    uint32_t pk = (uint32_t)(v.x & 255) | ((uint32_t)(v.y & 255) << 8) |
                  ((uint32_t)(v.z & 255) << 16) | ((uint32_t)(v.w & 255) << 24);
    reinterpret_cast<int*>(wout)[idx] = (int)pk;
}

// ---------------------------------------------------------------------------
// Kernel 1: per-token dynamic quantization.
// One block (256 threads) per token row of 4096 floats.
// q = clip(rint(x / (absmax/127)), -127, 127); store int8 row + scale.
// ---------------------------------------------------------------------------
__global__ __launch_bounds__(256) void quant_rows(const float* __restrict__ x,
                                                  int8_t* __restrict__ qx,
                                                  float* __restrict__ xscale) {
    const int t = blockIdx.x;
    const int tid = threadIdx.x;
    const float4* row = reinterpret_cast<const float4*>(x + (size_t)t * K_DIM);

    float4 v[4];
    float amax = 0.0f;
#pragma unroll
    for (int i = 0; i < 4; ++i) {
        v[i] = row[i * 256 + tid];
        amax = fmaxf(amax, fabsf(v[i].x));
        amax = fmaxf(amax, fabsf(v[i].y));
        amax = fmaxf(amax, fabsf(v[i].z));
        amax = fmaxf(amax, fabsf(v[i].w));
    }
    // wave (64-lane) butterfly max
#pragma unroll
    for (int off = 32; off > 0; off >>= 1)
        amax = fmaxf(amax, __shfl_xor(amax, off));

    __shared__ float red[4];
    if ((tid & 63) == 0) red[tid >> 6] = amax;
    __syncthreads();
    amax = fmaxf(fmaxf(red[0], red[1]), fmaxf(red[2], red[3]));

    const float scale = fmaxf(amax, 1e-30f) * (1.0f / 127.0f);
    if (tid == 0) xscale[t] = scale;

    int* qrow = reinterpret_cast<int*>(qx + (size_t)t * K_DIM);
#pragma unroll
    for (int i = 0; i < 4; ++i) {
        // exact division (matches reference x / x_scale), rint = round-nearest-even
        int q0 = (int)fminf(fmaxf(rintf(v[i].x / scale), -127.0f), 127.0f);
        int q1 = (int)fminf(fmaxf(rintf(v[i].y / scale), -127.0f), 127.0f);
        int q2 = (int)fminf(fmaxf(rintf(v[i].z / scale), -127.0f), 127.0f);
        int q3 = (int)fminf(fmaxf(rintf(v[i].w / scale), -127.0f), 127.0f);
        uint32_t pk = (uint32_t)(q0 & 255) | ((uint32_t)(q1 & 255) << 8) |
                      ((uint32_t)(q2 & 255) << 16) | ((uint32_t)(q3 & 255) << 24);
        qrow[i * 256 + tid] = (int)pk;
    }
}

// ---------------------------------------------------------------------------
// Kernel 2: int8 GEMM + dequant epilogue.
// C[t][n] = (sum_k qx[t][k]*w[n][k]) * wscale[n] * xscale[t] + bias[n]
// 128x128 tile per block, BK=64, 4 waves in 2x2, each wave 4x4 MFMAs of
// mfma_i32_16x16x64_i8. A-frag/B-frag: 16 contiguous K bytes per lane
// (idx = lane&15, kblock = lane>>4). C/D: col=lane&15, row=(lane>>4)*4+reg.
// ---------------------------------------------------------------------------
__global__ __launch_bounds__(256) void int8_gemm(const int8_t* __restrict__ qx,
                                                 const int8_t* __restrict__ w,
                                                 const float* __restrict__ xscale,
                                                 const float* __restrict__ wscale,
                                                 const float* __restrict__ bias,
                                                 float* __restrict__ out) {
    __shared__ int8_t As[128 * 64];  // [m][k] 64B rows
    __shared__ int8_t Bs[128 * 64];  // [n][k] 64B rows

    const int tid = threadIdx.x;
    const int lane = tid & 63;
    const int wave = tid >> 6;
    const int wr = wave >> 1;   // wave row (0..1) -> 64 tokens
    const int wc = wave & 1;    // wave col (0..1) -> 64 features
    const int l16 = lane & 15;
    const int quad = lane >> 4;

    const size_t a_row0 = (size_t)blockIdx.x * 128;
    const size_t b_row0 = (size_t)blockIdx.y * 128;

    // staging: thread tid loads rows (tid>>2) and (tid>>2)+64, 16B chunk (tid&3)
    const int s_row = tid >> 2;
    const int s_col = (tid & 3) * 16;

    const int8_t* ag0 = qx + (a_row0 + s_row) * (size_t)K_DIM + s_col;
    const int8_t* ag1 = ag0 + (size_t)64 * K_DIM;
    const int8_t* bg0 = w + (b_row0 + s_row) * (size_t)K_DIM + s_col;
    const int8_t* bg1 = bg0 + (size_t)64 * K_DIM;

    i32x4* As4 = reinterpret_cast<i32x4*>(As);
    i32x4* Bs4 = reinterpret_cast<i32x4*>(Bs);

    i32x4 acc[4][4] = {};

    // software pipeline: preload k0=0
    i32x4 ra0 = *reinterpret_cast<const i32x4*>(ag0);
    i32x4 ra1 = *reinterpret_cast<const i32x4*>(ag1);
    i32x4 rb0 = *reinterpret_cast<const i32x4*>(bg0);
    i32x4 rb1 = *reinterpret_cast<const i32x4*>(bg1);

    for (int k0 = 0; k0 < K_DIM; k0 += 64) {
        __syncthreads();  // prior iter's LDS reads done
        As4[tid] = ra0;
        As4[tid + 256] = ra1;
        Bs4[tid] = rb0;
        Bs4[tid + 256] = rb1;
        __syncthreads();

        const int k1 = k0 + 64;
        if (k1 < K_DIM) {  // issue next-iter global loads; overlap with MFMAs
            ra0 = *reinterpret_cast<const i32x4*>(ag0 + k1);
            ra1 = *reinterpret_cast<const i32x4*>(ag1 + k1);
            rb0 = *reinterpret_cast<const i32x4*>(bg0 + k1);
            rb1 = *reinterpret_cast<const i32x4*>(bg1 + k1);
        }

        i32x4 af[4], bf[4];
#pragma unroll
        for (int i = 0; i < 4; ++i) {
            af[i] = As4[((wr * 64 + i * 16 + l16) * 64 + quad * 16) >> 4];
            bf[i] = Bs4[((wc * 64 + i * 16 + l16) * 64 + quad * 16) >> 4];
        }
#pragma unroll
        for (int i = 0; i < 4; ++i)
#pragma unroll
            for (int j = 0; j < 4; ++j)
                acc[i][j] = __builtin_amdgcn_mfma_i32_16x16x64_i8(af[i], bf[j], acc[i][j], 0, 0, 0);
    }

    // epilogue: dequant + bias, scalar dword stores (C/D: col=l16, row=quad*4+r)
#pragma unroll
    for (int j = 0; j < 4; ++j) {
        const int n = (int)b_row0 + wc * 64 + j * 16 + l16;
        const float ws = wscale[n];
        const float bs = bias[n];
#pragma unroll
        for (int i = 0; i < 4; ++i) {
#pragma unroll
            for (int r = 0; r < 4; ++r) {
                const int t = (int)a_row0 + wr * 64 + i * 16 + quad * 4 + r;
                const float xs = xscale[t];
                out[(size_t)t * N_DIM + n] = (float)acc[i][j][r] * ws * xs + bs;
            }
        }
    }
}

extern "C" void kernel_launch(void* const* d_in, const int* in_sizes, int n_in,
                              void* d_out, int out_size, void* d_ws, size_t ws_size,
                              hipStream_t stream) {
    const float* x = (const float*)d_in[0];
    const int* w_i32 = (const int*)d_in[1];   // harness delivers int8 ref input as int32
    const float* wscale = (const float*)d_in[2];
    const float* bias = (const float*)d_in[3];
    float* out = (float*)d_out;

    // workspace: qx (32 MB) | xscale (32 KB) | packed weight (16 MB)
    int8_t* qx = (int8_t*)d_ws;
    float* xscale = (float*)((char*)d_ws + (size_t)T_TOKENS * K_DIM);
    int8_t* wpk = (int8_t*)((char*)d_ws + (size_t)T_TOKENS * K_DIM + 65536);

    // pack weight: 16.7M elements, 4 per thread
    pack_weight<<<(N_DIM * K_DIM / 4) / 256, 256, 0, stream>>>(w_i32, wpk);

    quant_rows<<<T_TOKENS, 256, 0, stream>>>(x, qx, xscale);

    dim3 grid(T_TOKENS / 128, N_DIM / 128);
    int8_gemm<<<grid, 256, 0, stream>>>(qx, wpk, xscale, wscale, bias, out);
}